// Round 5
// baseline (24523.697 us; speedup 1.0000x reference)
//
#include <hip/hip_runtime.h>
#include <math.h>

#define EPSN 1e-5f
#define BATCH 8
#define NCH 64
#define XROW 8192
#define L0IN 8128
#define L1P1 4058
#define LOUTP1 3968
#define WLEN 194
#define NSTEP 32
#define OUTROW 4000

__device__ __forceinline__ float gelu_f(float x){
    float x3 = x*x*x;
    return 0.5f*x*(1.0f + tanhf(0.7978845608028654f*(x + 0.044715f*x3)));
}

__device__ __forceinline__ float bn_gelu(float v, float sum, float sumsq, float invN, float s, float b){
    float m = sum*invN;
    float var = sumsq*invN - m*m;
    float rs = rsqrtf(var + EPSN);
    return gelu_f((v - m)*rs*s + b);
}

// ---------------- scalar stats (1-channel input), single block ----------------
__global__ void k_stats_scalar(const float* __restrict__ in, int bstride, int T, float* __restrict__ st){
    __shared__ float red[2048];
    int tid = threadIdx.x;
    float s = 0.f, sq = 0.f;
    int N = BATCH*T;
    for (int idx = tid; idx < N; idx += 1024){
        int b = idx / T, t = idx % T;
        float v = in[b*bstride + t];
        s += v; sq += v*v;
    }
    red[tid] = s; red[1024+tid] = sq;
    __syncthreads();
    for (int w = 512; w > 0; w >>= 1){
        if (tid < w){ red[tid] += red[tid+w]; red[1024+tid] += red[1024+tid+w]; }
        __syncthreads();
    }
    if (tid == 0){ st[0] = red[0]; st[1] = red[1024]; }
}

// ---------------- conv k=14 stride=2, 1ch input with analytic layer_in bn+gelu ----------------
__global__ void k_conv0(const float* __restrict__ in, int bstride, int Lin, int Lout,
                        const float* __restrict__ stX,
                        const float* __restrict__ w_in, const float* __restrict__ s_in, const float* __restrict__ b_in,
                        const float* __restrict__ w0,
                        float* __restrict__ out, float* __restrict__ stOut){
    __shared__ float lds[64*45];
    __shared__ float red[512];
    int b = blockIdx.y;
    int t0 = blockIdx.x * 16;
    int tid = threadIdx.x;
    int co = tid & 63, tg = tid >> 6;
    float invNx = 1.0f/(float)(BATCH*Lin);
    float mx = stX[0]*invNx;
    float vx = stX[1]*invNx - mx*mx;
    for (int idx = tid; idx < 44*64; idx += 256){
        int p = idx >> 6; int ci = idx & 63;
        int gp = 2*t0 + p;
        float val = 0.f;
        if (gp < Lin){
            float wc = w_in[ci];
            float raw = in[b*bstride + gp] * wc;
            float var = vx*wc*wc;
            float rs = rsqrtf(var + EPSN);
            val = gelu_f((raw - mx*wc)*rs*s_in[ci] + b_in[ci]);
        }
        lds[ci*45 + p] = val;
    }
    __syncthreads();
    float acc[4] = {0.f,0.f,0.f,0.f};
    for (int ci = 0; ci < 64; ++ci){
        float r[20];
        #pragma unroll
        for (int q = 0; q < 20; ++q) r[q] = lds[ci*45 + 8*tg + q];
        #pragma unroll
        for (int k = 0; k < 14; ++k){
            float w = w0[(k*64+ci)*64 + co];
            #pragma unroll
            for (int j = 0; j < 4; ++j) acc[j] = fmaf(r[2*j+k], w, acc[j]);
        }
    }
    float s = 0.f, sq = 0.f;
    #pragma unroll
    for (int j = 0; j < 4; ++j){
        int t = t0 + tg*4 + j;
        if (t < Lout){
            out[(b*Lout + t)*64 + co] = acc[j];
            s += acc[j]; sq += acc[j]*acc[j];
        }
    }
    red[tid] = s; red[256+tid] = sq;
    __syncthreads();
    if (tg == 0){
        float S  = red[co] + red[co+64] + red[co+128] + red[co+192];
        float SQ = red[256+co] + red[256+co+64] + red[256+co+128] + red[256+co+192];
        atomicAdd(&stOut[2*co],   S);
        atomicAdd(&stOut[2*co+1], SQ);
    }
}

// ---------------- conv k=7 stride=1, input = g(P) applied in LDS stage ----------------
__global__ void k_conv7(const float* __restrict__ P, int LP,
                        const float* __restrict__ stP, const float* __restrict__ s2, const float* __restrict__ b2,
                        const float* __restrict__ w,
                        float* __restrict__ Q, int LQ, float* __restrict__ stQ){
    __shared__ float lds[64*23];
    __shared__ float red[512];
    int b = blockIdx.y;
    int t0 = blockIdx.x * 16;
    int tid = threadIdx.x;
    int co = tid & 63, tg = tid >> 6;
    float invNp = 1.0f/(float)(BATCH*LP);
    for (int idx = tid; idx < 22*64; idx += 256){
        int p = idx >> 6; int ci = idx & 63;
        int gt = t0 + p;
        float val = 0.f;
        if (gt < LP){
            float raw = P[(b*LP + gt)*64 + ci];
            val = bn_gelu(raw, stP[2*ci], stP[2*ci+1], invNp, s2[ci], b2[ci]);
        }
        lds[ci*23 + p] = val;
    }
    __syncthreads();
    float acc[4] = {0.f,0.f,0.f,0.f};
    for (int ci = 0; ci < 64; ++ci){
        float r[10];
        #pragma unroll
        for (int q = 0; q < 10; ++q) r[q] = lds[ci*23 + tg*4 + q];
        #pragma unroll
        for (int k = 0; k < 7; ++k){
            float wv = w[(k*64+ci)*64 + co];
            #pragma unroll
            for (int j = 0; j < 4; ++j) acc[j] = fmaf(r[j+k], wv, acc[j]);
        }
    }
    float s = 0.f, sq = 0.f;
    #pragma unroll
    for (int j = 0; j < 4; ++j){
        int t = t0 + tg*4 + j;
        if (t < LQ){
            Q[(b*LQ + t)*64 + co] = acc[j];
            s += acc[j]; sq += acc[j]*acc[j];
        }
    }
    red[tid] = s; red[256+tid] = sq;
    __syncthreads();
    if (tg == 0){
        float S  = red[co] + red[co+64] + red[co+128] + red[co+192];
        float SQ = red[256+co] + red[256+co+64] + red[256+co+128] + red[256+co+192];
        atomicAdd(&stQ[2*co],   S);
        atomicAdd(&stQ[2*co+1], SQ);
    }
}

// ---------------- elementwise: Q = gelu(bn1(Q_raw)) [+ g(P[t+6])*wsk], stats of result ----------------
__global__ void k_elem(float* __restrict__ Q, int LQ,
                       const float* __restrict__ stQ, const float* __restrict__ s1, const float* __restrict__ b1,
                       const float* __restrict__ P, int LP,
                       const float* __restrict__ stP, const float* __restrict__ s2, const float* __restrict__ b2,
                       const float* __restrict__ wsk,
                       float* __restrict__ stOut){
    __shared__ float red[512];
    int tid = threadIdx.x;
    int c = tid & 63;
    int N = BATCH*LQ*64;
    int stride = gridDim.x*blockDim.x;
    float invNq = 1.0f/(float)(BATCH*LQ);
    float invNp = P ? 1.0f/(float)(BATCH*LP) : 0.f;
    float s = 0.f, sq = 0.f;
    for (int idx = blockIdx.x*blockDim.x + tid; idx < N; idx += stride){
        float v = Q[idx];
        float y = bn_gelu(v, stQ[2*c], stQ[2*c+1], invNq, s1[c], b1[c]);
        if (P){
            int bt = idx >> 6;
            int t  = bt % LQ;
            int bb = bt / LQ;
            float pv = P[(bb*LP + t + 6)*64 + c];
            y += bn_gelu(pv, stP[2*c], stP[2*c+1], invNp, s2[c], b2[c]) * wsk[c];
        }
        Q[idx] = y;
        s += y; sq += y*y;
    }
    red[tid] = s; red[256+tid] = sq;
    __syncthreads();
    if (tid < 64){
        float S  = red[c] + red[c+64] + red[c+128] + red[c+192];
        float SQ = red[256+c] + red[256+c+64] + red[256+c+128] + red[256+c+192];
        atomicAdd(&stOut[2*c],   S);
        atomicAdd(&stOut[2*c+1], SQ);
    }
}

// ---------------- output conv (64->1) with scalar stats ----------------
__global__ void k_convout(const float* __restrict__ P, int LQ,
                          const float* __restrict__ stP, const float* __restrict__ s2, const float* __restrict__ b2,
                          const float* __restrict__ w_out,
                          float* __restrict__ o_raw, float* __restrict__ stOut){
    __shared__ float red[8];
    int tid = threadIdx.x;
    int c = tid & 63, tq = tid >> 6;
    int M = BATCH*LQ;
    float invNp = 1.0f/(float)(BATCH*LQ);
    float myw = w_out[c];
    float ms = stP[2*c], msq = stP[2*c+1], ss = s2[c], bb = b2[c];
    float ls = 0.f, lq = 0.f;
    for (int m = blockIdx.x*4 + tq; m < M; m += gridDim.x*4){
        float pv = P[m*64 + c];
        float val = bn_gelu(pv, ms, msq, invNp, ss, bb) * myw;
        #pragma unroll
        for (int off = 32; off > 0; off >>= 1) val += __shfl_down(val, off, 64);
        if (c == 0){ o_raw[m] = val; ls += val; lq += val*val; }
    }
    if (c == 0){ red[tq] = ls; red[4+tq] = lq; }
    __syncthreads();
    if (tid == 0){
        atomicAdd(&stOut[0], red[0]+red[1]+red[2]+red[3]);
        atomicAdd(&stOut[1], red[4]+red[5]+red[6]+red[7]);
    }
}

// ---------------- phase-1 finalize: z0 -> d_out ----------------
__global__ void k_finalize1(const float* __restrict__ o_raw, const float* __restrict__ st,
                            const float* __restrict__ s_out, const float* __restrict__ b_out,
                            float* __restrict__ out){
    float invN = 1.0f/(float)(BATCH*LOUTP1);
    float m = st[0]*invN;
    float var = st[1]*invN - m*m;
    float rs = rsqrtf(var + EPSN);
    float so = s_out[0], bo = b_out[0];
    int N = BATCH*LOUTP1;
    for (int idx = blockIdx.x*blockDim.x + threadIdx.x; idx < N; idx += gridDim.x*blockDim.x){
        int b = idx / LOUTP1, t = idx % LOUTP1;
        out[b*OUTROW + t] = (o_raw[idx]-m)*rs*so + bo;
    }
}

// ---------------- init rolling window W1 = [x[7936:8128], x[8128], z0_last]; + its stats ----------------
__global__ void k_initW(const float* __restrict__ x, const float* __restrict__ out,
                        float* __restrict__ W, float* __restrict__ stX){
    __shared__ float red[512];
    int tid = threadIdx.x;
    float s = 0.f, sq = 0.f;
    for (int idx = tid; idx < BATCH*WLEN; idx += 256){
        int b = idx / WLEN, j = idx % WLEN;
        float v;
        if (j < 192)       v = x[b*XROW + 7936 + j];
        else if (j == 192) v = x[b*XROW + 8128];
        else               v = out[b*OUTROW + 3967];
        W[b*WLEN + j] = v;
        s += v; sq += v*v;
    }
    red[tid] = s; red[256+tid] = sq;
    __syncthreads();
    for (int w = 128; w > 0; w >>= 1){
        if (tid < w){ red[tid] += red[tid+w]; red[256+tid] += red[256+tid+w]; }
        __syncthreads();
    }
    if (tid == 0){ stX[0] = red[0]; stX[1] = red[256]; }
}

// ================= PHASE 2: one persistent cooperative kernel =================
#define G2 64
#define NTH2 256
#define P2STRIDE (G2*NTH2)

struct P2A {
    const float* x;
    float* out;
    float* W;          // 8*194 rolling window
    float* stx;        // window stats (2)
    float* bufA;       // 8*91*64
    float* bufB;       // 8*91*64
    float* pst;        // 32 steps * 32 slots * 128
    int*   bar;        // {cnt, gen}
    const float* w_in; const float* s_in; const float* b_in;
    const float* w0;
    const float* wconv; const float* wskip; const float* wout;
    const float* s0a; const float* b0a; const float* s0b; const float* b0b;
    const float* sa; const float* ba; const float* sb; const float* bbv;
    const float* s_out; const float* b_out;
};

__device__ __forceinline__ void gsync(int* bar){
    __threadfence();
    __syncthreads();
    if (threadIdx.x == 0){
        int g = __hip_atomic_load(&bar[1], __ATOMIC_RELAXED, __HIP_MEMORY_SCOPE_AGENT);
        int a = __hip_atomic_fetch_add(&bar[0], 1, __ATOMIC_ACQ_REL, __HIP_MEMORY_SCOPE_AGENT);
        if (a == G2-1){
            __hip_atomic_store(&bar[0], 0, __ATOMIC_RELAXED, __HIP_MEMORY_SCOPE_AGENT);
            __hip_atomic_store(&bar[1], g+1, __ATOMIC_RELEASE, __HIP_MEMORY_SCOPE_AGENT);
        } else {
            while (__hip_atomic_load(&bar[1], __ATOMIC_ACQUIRE, __HIP_MEMORY_SCOPE_AGENT) == g){
                __builtin_amdgcn_s_sleep(1);
            }
        }
    }
    __syncthreads();
}

__global__ __launch_bounds__(NTH2) void k_phase2(P2A a){
    __shared__ float lds[64*45];
    __shared__ float red[2*NTH2];
    __shared__ float shv[16];
    const int tid = threadIdx.x;
    const int wg  = blockIdx.x;
    const int gt  = wg*NTH2 + tid;
    const int co  = tid & 63, tg = tid >> 6;

    for (int i = gt; i < 32*32*128; i += P2STRIDE) a.pst[i] = 0.f;
    gsync(a.bar);

    float* PA = a.bufA;
    float* PB = a.bufB;

    for (int k = 0; k < NSTEP; ++k){
        float* pstep = a.pst + k*32*128;
        // ---------- S0: conv0 on window ----------
        {
            float invN = 1.0f/(8.0f*194.0f);
            float mx = a.stx[0]*invN;
            float vx = a.stx[1]*invN - mx*mx;
            float s = 0.f, sq = 0.f;
            for (int vb = wg; vb < 48; vb += G2){
                int b = vb / 6, xb = vb % 6;
                int t0 = xb*16;
                for (int idx = tid; idx < 44*64; idx += NTH2){
                    int p = idx >> 6, ci = idx & 63;
                    int gp = 2*t0 + p;
                    float val = 0.f;
                    if (gp < 194){
                        float wc = a.w_in[ci];
                        float raw = a.W[b*194 + gp]*wc;
                        float var = vx*wc*wc;
                        float rs = rsqrtf(var + EPSN);
                        val = gelu_f((raw - mx*wc)*rs*a.s_in[ci] + a.b_in[ci]);
                    }
                    lds[ci*45 + p] = val;
                }
                __syncthreads();
                float acc[4] = {0.f,0.f,0.f,0.f};
                for (int ci = 0; ci < 64; ++ci){
                    float r[20];
                    #pragma unroll
                    for (int q = 0; q < 20; ++q) r[q] = lds[ci*45 + 8*tg + q];
                    #pragma unroll
                    for (int kk = 0; kk < 14; ++kk){
                        float w = a.w0[(kk*64+ci)*64 + co];
                        #pragma unroll
                        for (int j = 0; j < 4; ++j) acc[j] = fmaf(r[2*j+kk], w, acc[j]);
                    }
                }
                #pragma unroll
                for (int j = 0; j < 4; ++j){
                    int t = t0 + tg*4 + j;
                    if (t < 91){
                        PA[(b*91 + t)*64 + co] = acc[j];
                        s += acc[j]; sq += acc[j]*acc[j];
                    }
                }
                __syncthreads();
            }
            red[tid] = s; red[NTH2+tid] = sq;
            __syncthreads();
            if (tg == 0 && wg < 48){
                float S  = red[co]+red[co+64]+red[co+128]+red[co+192];
                float SQ = red[NTH2+co]+red[NTH2+co+64]+red[NTH2+co+128]+red[NTH2+co+192];
                atomicAdd(&pstep[2*co],   S);
                atomicAdd(&pstep[2*co+1], SQ);
            }
        }
        gsync(a.bar);
        // ---------- S1: elem0 ----------
        {
            float* stB = pstep;
            float* stC = pstep + 128;
            const float invNq = 1.0f/(8.0f*91.0f);
            float s = 0.f, sq = 0.f;
            for (int idx = gt; idx < 8*91*64; idx += P2STRIDE){
                int c = idx & 63;
                float y = bn_gelu(PA[idx], stB[2*c], stB[2*c+1], invNq, a.s0a[c], a.b0a[c]);
                PA[idx] = y; s += y; sq += y*y;
            }
            red[tid] = s; red[NTH2+tid] = sq;
            __syncthreads();
            if (tg == 0){
                float S  = red[co]+red[co+64]+red[co+128]+red[co+192];
                float SQ = red[NTH2+co]+red[NTH2+co+64]+red[NTH2+co+128]+red[NTH2+co+192];
                atomicAdd(&stC[2*co],   S);
                atomicAdd(&stC[2*co+1], SQ);
            }
        }
        gsync(a.bar);
        // ---------- 15 layers ----------
        const float* stP = pstep + 128;
        const float* cs2 = a.s0b; const float* cb2 = a.b0b;
        int LP = 91;
        for (int i = 0; i < 15; ++i){
            int LQ = LP - 6;
            float* stY  = pstep + (2+2*i)*128;
            float* stY2 = pstep + (3+2*i)*128;
            const float* wv = a.wconv + (size_t)i*7*64*64;
            float invNp = 1.0f/(8.0f*(float)LP);
            int nb = (LQ + 15)/16;
            // conv
            {
                float s = 0.f, sq = 0.f;
                for (int vb = wg; vb < nb*8; vb += G2){
                    int b = vb / nb, xb = vb % nb;
                    int t0 = xb*16;
                    for (int idx = tid; idx < 22*64; idx += NTH2){
                        int p = idx >> 6, ci = idx & 63;
                        int gtp = t0 + p;
                        float val = 0.f;
                        if (gtp < LP)
                            val = bn_gelu(PA[(b*LP+gtp)*64+ci], stP[2*ci], stP[2*ci+1], invNp, cs2[ci], cb2[ci]);
                        lds[ci*23 + p] = val;
                    }
                    __syncthreads();
                    float acc[4] = {0.f,0.f,0.f,0.f};
                    for (int ci = 0; ci < 64; ++ci){
                        float r[10];
                        #pragma unroll
                        for (int q = 0; q < 10; ++q) r[q] = lds[ci*23 + tg*4 + q];
                        #pragma unroll
                        for (int kk = 0; kk < 7; ++kk){
                            float w = wv[(kk*64+ci)*64 + co];
                            #pragma unroll
                            for (int j = 0; j < 4; ++j) acc[j] = fmaf(r[j+kk], w, acc[j]);
                        }
                    }
                    #pragma unroll
                    for (int j = 0; j < 4; ++j){
                        int t = t0 + tg*4 + j;
                        if (t < LQ){
                            PB[(b*LQ+t)*64+co] = acc[j];
                            s += acc[j]; sq += acc[j]*acc[j];
                        }
                    }
                    __syncthreads();
                }
                red[tid] = s; red[NTH2+tid] = sq;
                __syncthreads();
                if (tg == 0 && wg < nb*8){
                    float S  = red[co]+red[co+64]+red[co+128]+red[co+192];
                    float SQ = red[NTH2+co]+red[NTH2+co+64]+red[NTH2+co+128]+red[NTH2+co+192];
                    atomicAdd(&stY[2*co],   S);
                    atomicAdd(&stY[2*co+1], SQ);
                }
            }
            gsync(a.bar);
            // elem (+skip)
            {
                const float* sa_i = a.sa + 64*i; const float* ba_i = a.ba + 64*i;
                const float* wsk  = a.wskip + 64*i;
                float invNq2 = 1.0f/(8.0f*(float)LQ);
                float s = 0.f, sq = 0.f;
                for (int idx = gt; idx < 8*LQ*64; idx += P2STRIDE){
                    int c  = idx & 63;
                    int bt = idx >> 6;
                    int t  = bt % LQ, b = bt / LQ;
                    float y = bn_gelu(PB[idx], stY[2*c], stY[2*c+1], invNq2, sa_i[c], ba_i[c]);
                    y += bn_gelu(PA[(b*LP + t + 6)*64 + c], stP[2*c], stP[2*c+1], invNp, cs2[c], cb2[c]) * wsk[c];
                    PB[idx] = y; s += y; sq += y*y;
                }
                red[tid] = s; red[NTH2+tid] = sq;
                __syncthreads();
                if (tg == 0){
                    float S  = red[co]+red[co+64]+red[co+128]+red[co+192];
                    float SQ = red[NTH2+co]+red[NTH2+co+64]+red[NTH2+co+128]+red[NTH2+co+192];
                    atomicAdd(&stY2[2*co],   S);
                    atomicAdd(&stY2[2*co+1], SQ);
                }
            }
            gsync(a.bar);
            stP = stY2; cs2 = a.sb + 64*i; cb2 = a.bbv + 64*i;
            float* tmp = PA; PA = PB; PB = tmp;
            LP = LQ;
        }
        // ---------- OUT stage (WG0): out conv, sample, next window ----------
        if (wg == 0){
            const float invNp = 0.125f;
            if (tid < 64){
                int c = tid;
                float ms = stP[2*c], mq = stP[2*c+1];
                float s2v = cs2[c], b2v = cb2[c];
                float wo = a.wout[c];
                float contrib[8];
                #pragma unroll
                for (int b = 0; b < 8; ++b)
                    contrib[b] = bn_gelu(PA[b*64 + c], ms, mq, invNp, s2v, b2v) * wo;
                #pragma unroll
                for (int b = 0; b < 8; ++b){
                    float v = contrib[b];
                    #pragma unroll
                    for (int off = 32; off > 0; off >>= 1) v += __shfl_down(v, off, 64);
                    if (c == 0) shv[b] = v;
                }
            }
            __syncthreads();
            if (tid == 0){
                float m = 0.f, q = 0.f;
                #pragma unroll
                for (int b = 0; b < 8; ++b){ m += shv[b]; q += shv[b]*shv[b]; }
                m *= 0.125f;
                float var = q*0.125f - m*m;
                float rs = rsqrtf(var + EPSN);
                float so = a.s_out[0], bo = a.b_out[0];
                #pragma unroll
                for (int b = 0; b < 8; ++b){
                    float v = (shv[b]-m)*rs*so + bo;
                    shv[8+b] = v;
                    a.out[b*OUTROW + 3968 + k] = v;
                }
            }
            __syncthreads();
            if (k < NSTEP-1){
                for (int idx = tid; idx < 8*194; idx += NTH2) lds[idx] = a.W[idx];
                __syncthreads();
                float s = 0.f, sq = 0.f;
                for (int idx = tid; idx < 8*194; idx += NTH2){
                    int b = idx / 194, j = idx % 194;
                    float v;
                    if (j < 192)       v = lds[b*194 + j + 2];
                    else if (j == 192) v = a.x[b*XROW + L0IN + 2*(k+1)];
                    else               v = shv[8+b];
                    a.W[idx] = v;
                    s += v; sq += v*v;
                }
                red[tid] = s; red[NTH2+tid] = sq;
                __syncthreads();
                for (int w = 128; w > 0; w >>= 1){
                    if (tid < w){ red[tid] += red[tid+w]; red[NTH2+tid] += red[NTH2+tid+w]; }
                    __syncthreads();
                }
                if (tid == 0){ a.stx[0] = red[0]; a.stx[1] = red[NTH2]; }
            }
        }
        gsync(a.bar);
    }
}

static inline int imin(int a, int b){ return a < b ? a : b; }

extern "C" void kernel_launch(void* const* d_in, const int* in_sizes, int n_in,
                              void* d_out, int out_size, void* d_ws, size_t ws_size,
                              hipStream_t stream){
    const float* x      = (const float*)d_in[0];
    const float* w_in   = (const float*)d_in[1];
    const float* w0     = (const float*)d_in[2];
    const float* w_conv = (const float*)d_in[3];
    const float* w_skip = (const float*)d_in[4];
    const float* w_out  = (const float*)d_in[5];
    const float* s_in   = (const float*)d_in[6];
    const float* b_in   = (const float*)d_in[7];
    const float* s0a    = (const float*)d_in[8];
    const float* b0a    = (const float*)d_in[9];
    const float* s0b    = (const float*)d_in[10];
    const float* b0b    = (const float*)d_in[11];
    const float* sa     = (const float*)d_in[12];
    const float* ba     = (const float*)d_in[13];
    const float* sb     = (const float*)d_in[14];
    const float* bb     = (const float*)d_in[15];
    const float* s_out  = (const float*)d_in[16];
    const float* b_out  = (const float*)d_in[17];
    float* out = (float*)d_out;

    float* ws = (float*)d_ws;
    size_t off = 0;
    float* buf0  = ws + off; off += (size_t)BATCH*L1P1*64;
    float* buf1  = ws + off; off += (size_t)BATCH*L1P1*64;
    float* o_raw = ws + off; off += BATCH*LOUTP1;
    float* W0    = ws + off; off += BATCH*WLEN;
    float* W1    = ws + off; off += BATCH*WLEN;
    float* stats = ws + off; off += 4104;
    float* STX = stats;
    float* STB = stats + 2;
    float* STC = stats + 130;
    float* STOUT = stats + 4098;
    int* bar = (int*)(stats + 4100);

    // phase-2 overlays (buf0 is free once phase 1 completes)
    float* P2A_buf = buf0;
    float* P2B_buf = buf0 + 8*91*64;
    float* P2_pst  = buf0 + 2*8*91*64;

    hipMemsetAsync((void*)bar, 0, 2*sizeof(int), stream);

    // -------- phase 1 (multi-kernel pipeline) --------
    hipMemsetAsync((void*)STX, 0, 2*sizeof(float), stream);
    k_stats_scalar<<<1, 1024, 0, stream>>>(x, XROW, L0IN, STX);

    {
        int Lin = L0IN;
        int Lc = (Lin - 14)/2 + 1;
        // IMPORTANT: must cover STB..STOUT inclusive (stats+2 .. stats+4099).
        // Round-3 bug: 4096 here left STOUT un-zeroed -> accumulation across graph replays.
        hipMemsetAsync((void*)STB, 0, 4098*sizeof(float), stream);
        k_conv0<<<dim3((Lc+15)/16, BATCH), 256, 0, stream>>>(x, XROW, Lin, Lc, STX,
                                                             w_in, s_in, b_in, w0, buf0, STB);
        {
            int N = BATCH*Lc*64;
            int g = imin((N+255)/256, 2048);
            k_elem<<<g, 256, 0, stream>>>(buf0, Lc, STB, s0a, b0a,
                                          nullptr, 0, nullptr, nullptr, nullptr, nullptr, STC);
        }
        float* A = buf0; float* Bf = buf1;
        const float* stP = STC; const float* cs2 = s0b; const float* cb2 = b0b;
        int LP = Lc;
        for (int i = 0; i < 15; ++i){
            int LQ = LP - 6;
            float* stY  = stats + 258 + i*256;
            float* stY2 = stY + 128;
            k_conv7<<<dim3((LQ+15)/16, BATCH), 256, 0, stream>>>(A, LP, stP, cs2, cb2,
                                                                 w_conv + (size_t)i*7*64*64, Bf, LQ, stY);
            int N = BATCH*LQ*64;
            int g = imin((N+255)/256, 2048);
            k_elem<<<g, 256, 0, stream>>>(Bf, LQ, stY, sa + 64*i, ba + 64*i,
                                          A, LP, stP, cs2, cb2, w_skip + 64*i, stY2);
            stP = stY2; cs2 = sb + 64*i; cb2 = bb + 64*i;
            float* tmp = A; A = Bf; Bf = tmp;
            LP = LQ;
        }
        int g = imin((BATCH*LP+3)/4, 512);
        k_convout<<<g, 256, 0, stream>>>(A, LP, stP, cs2, cb2, w_out, o_raw, STOUT);
    }
    k_finalize1<<<imin((BATCH*LOUTP1+255)/256, 512), 256, 0, stream>>>(o_raw, STOUT, s_out, b_out, out);
    k_initW<<<1, 256, 0, stream>>>(x, out, W0, STX);

    // -------- phase 2: one persistent cooperative kernel --------
    P2A pa;
    pa.x = x; pa.out = out; pa.W = W0; pa.stx = STX;
    pa.bufA = P2A_buf; pa.bufB = P2B_buf; pa.pst = P2_pst; pa.bar = bar;
    pa.w_in = w_in; pa.s_in = s_in; pa.b_in = b_in;
    pa.w0 = w0; pa.wconv = w_conv; pa.wskip = w_skip; pa.wout = w_out;
    pa.s0a = s0a; pa.b0a = b0a; pa.s0b = s0b; pa.b0b = b0b;
    pa.sa = sa; pa.ba = ba; pa.sb = sb; pa.bbv = bb;
    pa.s_out = s_out; pa.b_out = b_out;

    void* kargs[] = { (void*)&pa };
    hipError_t err = hipLaunchCooperativeKernel((const void*)k_phase2, dim3(G2), dim3(NTH2),
                                                kargs, 0, stream);
    if (err != hipSuccess){
        // 64 WGs x 256 threads is trivially co-resident on 256 CUs
        k_phase2<<<dim3(G2), dim3(NTH2), 0, stream>>>(pa);
    }
}

// Round 6
// 17748.611 us; speedup vs baseline: 1.3817x; 1.3817x over previous
//
#include <hip/hip_runtime.h>
#include <math.h>

#define EPSN 1e-5f
#define BATCH 8
#define NCH 64
#define XROW 8192
#define L0IN 8128
#define L1P1 4058
#define LOUTP1 3968
#define WLEN 194
#define NSTEP 32
#define OUTROW 4000

__device__ __forceinline__ float gelu_f(float x){
    float x3 = x*x*x;
    return 0.5f*x*(1.0f + tanhf(0.7978845608028654f*(x + 0.044715f*x3)));
}

__device__ __forceinline__ float bn_gelu(float v, float sum, float sumsq, float invN, float s, float b){
    float m = sum*invN;
    float var = sumsq*invN - m*m;
    float rs = rsqrtf(var + EPSN);
    return gelu_f((v - m)*rs*s + b);
}

// ---------------- scalar stats (1-channel input), single block ----------------
__global__ void k_stats_scalar(const float* __restrict__ in, int bstride, int T, float* __restrict__ st){
    __shared__ float red[2048];
    int tid = threadIdx.x;
    float s = 0.f, sq = 0.f;
    int N = BATCH*T;
    for (int idx = tid; idx < N; idx += 1024){
        int b = idx / T, t = idx % T;
        float v = in[b*bstride + t];
        s += v; sq += v*v;
    }
    red[tid] = s; red[1024+tid] = sq;
    __syncthreads();
    for (int w = 512; w > 0; w >>= 1){
        if (tid < w){ red[tid] += red[tid+w]; red[1024+tid] += red[1024+tid+w]; }
        __syncthreads();
    }
    if (tid == 0){ st[0] = red[0]; st[1] = red[1024]; }
}

// ---------------- conv k=14 stride=2, 1ch input with analytic layer_in bn+gelu ----------------
__global__ void k_conv0(const float* __restrict__ in, int bstride, int Lin, int Lout,
                        const float* __restrict__ stX,
                        const float* __restrict__ w_in, const float* __restrict__ s_in, const float* __restrict__ b_in,
                        const float* __restrict__ w0,
                        float* __restrict__ out, float* __restrict__ stOut){
    __shared__ float lds[64*45];
    __shared__ float red[512];
    int b = blockIdx.y;
    int t0 = blockIdx.x * 16;
    int tid = threadIdx.x;
    int co = tid & 63, tg = tid >> 6;
    float invNx = 1.0f/(float)(BATCH*Lin);
    float mx = stX[0]*invNx;
    float vx = stX[1]*invNx - mx*mx;
    for (int idx = tid; idx < 44*64; idx += 256){
        int p = idx >> 6; int ci = idx & 63;
        int gp = 2*t0 + p;
        float val = 0.f;
        if (gp < Lin){
            float wc = w_in[ci];
            float raw = in[b*bstride + gp] * wc;
            float var = vx*wc*wc;
            float rs = rsqrtf(var + EPSN);
            val = gelu_f((raw - mx*wc)*rs*s_in[ci] + b_in[ci]);
        }
        lds[ci*45 + p] = val;
    }
    __syncthreads();
    float acc[4] = {0.f,0.f,0.f,0.f};
    for (int ci = 0; ci < 64; ++ci){
        float r[20];
        #pragma unroll
        for (int q = 0; q < 20; ++q) r[q] = lds[ci*45 + 8*tg + q];
        #pragma unroll
        for (int k = 0; k < 14; ++k){
            float w = w0[(k*64+ci)*64 + co];
            #pragma unroll
            for (int j = 0; j < 4; ++j) acc[j] = fmaf(r[2*j+k], w, acc[j]);
        }
    }
    float s = 0.f, sq = 0.f;
    #pragma unroll
    for (int j = 0; j < 4; ++j){
        int t = t0 + tg*4 + j;
        if (t < Lout){
            out[(b*Lout + t)*64 + co] = acc[j];
            s += acc[j]; sq += acc[j]*acc[j];
        }
    }
    red[tid] = s; red[256+tid] = sq;
    __syncthreads();
    if (tg == 0){
        float S  = red[co] + red[co+64] + red[co+128] + red[co+192];
        float SQ = red[256+co] + red[256+co+64] + red[256+co+128] + red[256+co+192];
        atomicAdd(&stOut[2*co],   S);
        atomicAdd(&stOut[2*co+1], SQ);
    }
}

// ---------------- conv k=7 stride=1, input = g(P) applied in LDS stage ----------------
__global__ void k_conv7(const float* __restrict__ P, int LP,
                        const float* __restrict__ stP, const float* __restrict__ s2, const float* __restrict__ b2,
                        const float* __restrict__ w,
                        float* __restrict__ Q, int LQ, float* __restrict__ stQ){
    __shared__ float lds[64*23];
    __shared__ float red[512];
    int b = blockIdx.y;
    int t0 = blockIdx.x * 16;
    int tid = threadIdx.x;
    int co = tid & 63, tg = tid >> 6;
    float invNp = 1.0f/(float)(BATCH*LP);
    for (int idx = tid; idx < 22*64; idx += 256){
        int p = idx >> 6; int ci = idx & 63;
        int gt = t0 + p;
        float val = 0.f;
        if (gt < LP){
            float raw = P[(b*LP + gt)*64 + ci];
            val = bn_gelu(raw, stP[2*ci], stP[2*ci+1], invNp, s2[ci], b2[ci]);
        }
        lds[ci*23 + p] = val;
    }
    __syncthreads();
    float acc[4] = {0.f,0.f,0.f,0.f};
    for (int ci = 0; ci < 64; ++ci){
        float r[10];
        #pragma unroll
        for (int q = 0; q < 10; ++q) r[q] = lds[ci*23 + tg*4 + q];
        #pragma unroll
        for (int k = 0; k < 7; ++k){
            float wv = w[(k*64+ci)*64 + co];
            #pragma unroll
            for (int j = 0; j < 4; ++j) acc[j] = fmaf(r[j+k], wv, acc[j]);
        }
    }
    float s = 0.f, sq = 0.f;
    #pragma unroll
    for (int j = 0; j < 4; ++j){
        int t = t0 + tg*4 + j;
        if (t < LQ){
            Q[(b*LQ + t)*64 + co] = acc[j];
            s += acc[j]; sq += acc[j]*acc[j];
        }
    }
    red[tid] = s; red[256+tid] = sq;
    __syncthreads();
    if (tg == 0){
        float S  = red[co] + red[co+64] + red[co+128] + red[co+192];
        float SQ = red[256+co] + red[256+co+64] + red[256+co+128] + red[256+co+192];
        atomicAdd(&stQ[2*co],   S);
        atomicAdd(&stQ[2*co+1], SQ);
    }
}

// ---------------- elementwise: Q = gelu(bn1(Q_raw)) [+ g(P[t+6])*wsk], stats of result ----------------
__global__ void k_elem(float* __restrict__ Q, int LQ,
                       const float* __restrict__ stQ, const float* __restrict__ s1, const float* __restrict__ b1,
                       const float* __restrict__ P, int LP,
                       const float* __restrict__ stP, const float* __restrict__ s2, const float* __restrict__ b2,
                       const float* __restrict__ wsk,
                       float* __restrict__ stOut){
    __shared__ float red[512];
    int tid = threadIdx.x;
    int c = tid & 63;
    int N = BATCH*LQ*64;
    int stride = gridDim.x*blockDim.x;
    float invNq = 1.0f/(float)(BATCH*LQ);
    float invNp = P ? 1.0f/(float)(BATCH*LP) : 0.f;
    float s = 0.f, sq = 0.f;
    for (int idx = blockIdx.x*blockDim.x + tid; idx < N; idx += stride){
        float v = Q[idx];
        float y = bn_gelu(v, stQ[2*c], stQ[2*c+1], invNq, s1[c], b1[c]);
        if (P){
            int bt = idx >> 6;
            int t  = bt % LQ;
            int bb = bt / LQ;
            float pv = P[(bb*LP + t + 6)*64 + c];
            y += bn_gelu(pv, stP[2*c], stP[2*c+1], invNp, s2[c], b2[c]) * wsk[c];
        }
        Q[idx] = y;
        s += y; sq += y*y;
    }
    red[tid] = s; red[256+tid] = sq;
    __syncthreads();
    if (tid < 64){
        float S  = red[c] + red[c+64] + red[c+128] + red[c+192];
        float SQ = red[256+c] + red[256+c+64] + red[256+c+128] + red[256+c+192];
        atomicAdd(&stOut[2*c],   S);
        atomicAdd(&stOut[2*c+1], SQ);
    }
}

// ---------------- output conv (64->1) with scalar stats ----------------
__global__ void k_convout(const float* __restrict__ P, int LQ,
                          const float* __restrict__ stP, const float* __restrict__ s2, const float* __restrict__ b2,
                          const float* __restrict__ w_out,
                          float* __restrict__ o_raw, float* __restrict__ stOut){
    __shared__ float red[8];
    int tid = threadIdx.x;
    int c = tid & 63, tq = tid >> 6;
    int M = BATCH*LQ;
    float invNp = 1.0f/(float)(BATCH*LQ);
    float myw = w_out[c];
    float ms = stP[2*c], msq = stP[2*c+1], ss = s2[c], bb = b2[c];
    float ls = 0.f, lq = 0.f;
    for (int m = blockIdx.x*4 + tq; m < M; m += gridDim.x*4){
        float pv = P[m*64 + c];
        float val = bn_gelu(pv, ms, msq, invNp, ss, bb) * myw;
        #pragma unroll
        for (int off = 32; off > 0; off >>= 1) val += __shfl_down(val, off, 64);
        if (c == 0){ o_raw[m] = val; ls += val; lq += val*val; }
    }
    if (c == 0){ red[tq] = ls; red[4+tq] = lq; }
    __syncthreads();
    if (tid == 0){
        atomicAdd(&stOut[0], red[0]+red[1]+red[2]+red[3]);
        atomicAdd(&stOut[1], red[4]+red[5]+red[6]+red[7]);
    }
}

// ---------------- phase-1 finalize: z0 -> d_out ----------------
__global__ void k_finalize1(const float* __restrict__ o_raw, const float* __restrict__ st,
                            const float* __restrict__ s_out, const float* __restrict__ b_out,
                            float* __restrict__ out){
    float invN = 1.0f/(float)(BATCH*LOUTP1);
    float m = st[0]*invN;
    float var = st[1]*invN - m*m;
    float rs = rsqrtf(var + EPSN);
    float so = s_out[0], bo = b_out[0];
    int N = BATCH*LOUTP1;
    for (int idx = blockIdx.x*blockDim.x + threadIdx.x; idx < N; idx += gridDim.x*blockDim.x){
        int b = idx / LOUTP1, t = idx % LOUTP1;
        out[b*OUTROW + t] = (o_raw[idx]-m)*rs*so + bo;
    }
}

// ---------------- init rolling window W1 = [x[7936:8128], x[8128], z0_last]; + its stats ----------------
__global__ void k_initW(const float* __restrict__ x, const float* __restrict__ out,
                        float* __restrict__ W, float* __restrict__ stX){
    __shared__ float red[512];
    int tid = threadIdx.x;
    float s = 0.f, sq = 0.f;
    for (int idx = tid; idx < BATCH*WLEN; idx += 256){
        int b = idx / WLEN, j = idx % WLEN;
        float v;
        if (j < 192)       v = x[b*XROW + 7936 + j];
        else if (j == 192) v = x[b*XROW + 8128];
        else               v = out[b*OUTROW + 3967];
        W[b*WLEN + j] = v;
        s += v; sq += v*v;
    }
    red[tid] = s; red[256+tid] = sq;
    __syncthreads();
    for (int w = 128; w > 0; w >>= 1){
        if (tid < w){ red[tid] += red[tid+w]; red[256+tid] += red[256+tid+w]; }
        __syncthreads();
    }
    if (tid == 0){ stX[0] = red[0]; stX[1] = red[256]; }
}

// ================= PHASE 2: one persistent cooperative kernel =================
#define G2 64
#define NTH2 256
#define P2STRIDE (G2*NTH2)
#define PSTSET (32*128)

// L3-coherent (agent-scope) accessors: no dirty L2, no stale caches -> no fences needed.
__device__ __forceinline__ float ldc(const float* p){
    return __hip_atomic_load(p, __ATOMIC_RELAXED, __HIP_MEMORY_SCOPE_AGENT);
}
__device__ __forceinline__ void stc(float* p, float v){
    __hip_atomic_store(p, v, __ATOMIC_RELAXED, __HIP_MEMORY_SCOPE_AGENT);
}

struct P2A {
    const float* x;
    float* out;
    float* W;          // 8*194 rolling window (L3-coherent access)
    float* stx;        // window stats (2)
    float* bufA;       // 8*91*64
    float* bufB;       // 8*91*64
    float* pst;        // 2 sets x 32 slots x 128 (ping-pong, in o_raw region)
    int*   bar;        // {cnt, gen}
    const float* w_in; const float* s_in; const float* b_in;
    const float* w0;
    const float* wconv; const float* wskip; const float* wout;
    const float* s0a; const float* b0a; const float* s0b; const float* b0b;
    const float* sa; const float* ba; const float* sb; const float* bbv;
    const float* s_out; const float* b_out;
};

// All-relaxed barrier: no buffer_inv / buffer_wbl2 anywhere (round-5 post-mortem:
// acquire-per-poll invalidated L2 every spin iteration -> ~21us/barrier).
// Cross-WG data is exclusively L3-coherent (atomics + ldc/stc), so relaxed suffices.
__device__ __forceinline__ void gsync(int* bar){
    asm volatile("s_waitcnt vmcnt(0)" ::: "memory");  // this wave's stores complete at L3
    __syncthreads();                                  // all waves drained
    if (threadIdx.x == 0){
        int g = __hip_atomic_load(&bar[1], __ATOMIC_RELAXED, __HIP_MEMORY_SCOPE_AGENT);
        int a = __hip_atomic_fetch_add(&bar[0], 1, __ATOMIC_RELAXED, __HIP_MEMORY_SCOPE_AGENT);
        if (a == G2-1){
            __hip_atomic_store(&bar[0], 0, __ATOMIC_RELAXED, __HIP_MEMORY_SCOPE_AGENT);
            asm volatile("s_waitcnt vmcnt(0)" ::: "memory");  // reset lands before publish
            __hip_atomic_store(&bar[1], g+1, __ATOMIC_RELAXED, __HIP_MEMORY_SCOPE_AGENT);
        } else {
            while (__hip_atomic_load(&bar[1], __ATOMIC_RELAXED, __HIP_MEMORY_SCOPE_AGENT) == g){
                __builtin_amdgcn_s_sleep(4);
            }
        }
    }
    __syncthreads();
}

__global__ __launch_bounds__(NTH2) void k_phase2(P2A a){
    __shared__ float lds[64*45];
    __shared__ float red[2*NTH2];
    __shared__ float shv[16];
    __shared__ float sst[256];
    __shared__ float wloc[48];
    const int tid = threadIdx.x;
    const int wg  = blockIdx.x;
    const int gt  = wg*NTH2 + tid;
    const int co  = tid & 63, tg = tid >> 6;

    // zero both stat sets (o_raw region is dead after phase 1)
    for (int i = gt; i < 2*PSTSET; i += P2STRIDE) stc(&a.pst[i], 0.f);
    gsync(a.bar);

    float* PA = a.bufA;
    float* PB = a.bufB;

    for (int k = 0; k < NSTEP; ++k){
        float* pstep = a.pst + (k&1)*PSTSET;
        // ---------- S0: conv0 on window ----------
        {
            float invN = 1.0f/(8.0f*194.0f);
            float mx = ldc(&a.stx[0])*invN;
            float vx = ldc(&a.stx[1])*invN - mx*mx;
            float s = 0.f, sq = 0.f;
            for (int vb = wg; vb < 48; vb += G2){
                int b = vb / 6, xb = vb % 6;
                int t0 = xb*16;
                if (tid < 44){
                    int gp = 2*t0 + tid;
                    wloc[tid] = (gp < 194) ? ldc(&a.W[b*194 + gp]) : 0.f;
                }
                __syncthreads();
                for (int idx = tid; idx < 44*64; idx += NTH2){
                    int p = idx >> 6, ci = idx & 63;
                    int gp = 2*t0 + p;
                    float val = 0.f;
                    if (gp < 194){
                        float wc = a.w_in[ci];
                        float raw = wloc[p]*wc;
                        float var = vx*wc*wc;
                        float rs = rsqrtf(var + EPSN);
                        val = gelu_f((raw - mx*wc)*rs*a.s_in[ci] + a.b_in[ci]);
                    }
                    lds[ci*45 + p] = val;
                }
                __syncthreads();
                float acc[4] = {0.f,0.f,0.f,0.f};
                for (int ci = 0; ci < 64; ++ci){
                    float r[20];
                    #pragma unroll
                    for (int q = 0; q < 20; ++q) r[q] = lds[ci*45 + 8*tg + q];
                    #pragma unroll
                    for (int kk = 0; kk < 14; ++kk){
                        float w = a.w0[(kk*64+ci)*64 + co];
                        #pragma unroll
                        for (int j = 0; j < 4; ++j) acc[j] = fmaf(r[2*j+kk], w, acc[j]);
                    }
                }
                #pragma unroll
                for (int j = 0; j < 4; ++j){
                    int t = t0 + tg*4 + j;
                    if (t < 91){
                        stc(&PA[(b*91 + t)*64 + co], acc[j]);
                        s += acc[j]; sq += acc[j]*acc[j];
                    }
                }
                __syncthreads();
            }
            red[tid] = s; red[NTH2+tid] = sq;
            __syncthreads();
            if (tg == 0 && wg < 48){
                float S  = red[co]+red[co+64]+red[co+128]+red[co+192];
                float SQ = red[NTH2+co]+red[NTH2+co+64]+red[NTH2+co+128]+red[NTH2+co+192];
                atomicAdd(&pstep[2*co],   S);
                atomicAdd(&pstep[2*co+1], SQ);
            }
        }
        gsync(a.bar);
        // ---------- S1: elem0 (+ zero next stat set) ----------
        {
            if (tid < 128) sst[tid] = ldc(&pstep[tid]);
            __syncthreads();
            if (k < NSTEP-1){
                float* nz = a.pst + ((k+1)&1)*PSTSET;
                for (int idx = gt; idx < PSTSET; idx += P2STRIDE) stc(&nz[idx], 0.f);
            }
            const float invNq = 1.0f/(8.0f*91.0f);
            float s = 0.f, sq = 0.f;
            for (int idx = gt; idx < 8*91*64; idx += P2STRIDE){
                int c = idx & 63;
                float y = bn_gelu(ldc(&PA[idx]), sst[2*c], sst[2*c+1], invNq, a.s0a[c], a.b0a[c]);
                stc(&PA[idx], y); s += y; sq += y*y;
            }
            red[tid] = s; red[NTH2+tid] = sq;
            __syncthreads();
            if (tg == 0){
                float S  = red[co]+red[co+64]+red[co+128]+red[co+192];
                float SQ = red[NTH2+co]+red[NTH2+co+64]+red[NTH2+co+128]+red[NTH2+co+192];
                atomicAdd(&pstep[128 + 2*co],   S);
                atomicAdd(&pstep[128 + 2*co+1], SQ);
            }
        }
        gsync(a.bar);
        // ---------- 15 layers ----------
        float* stP = pstep + 128;
        const float* cs2 = a.s0b; const float* cb2 = a.b0b;
        int LP = 91;
        for (int i = 0; i < 15; ++i){
            int LQ = LP - 6;
            float* stY  = pstep + (2+2*i)*128;
            float* stY2 = pstep + (3+2*i)*128;
            const float* wv = a.wconv + (size_t)i*7*64*64;
            float invNp = 1.0f/(8.0f*(float)LP);
            int nb = (LQ + 15)/16;
            // conv
            {
                if (tid < 128) sst[tid] = ldc(&stP[tid]);
                __syncthreads();
                float s = 0.f, sq = 0.f;
                for (int vb = wg; vb < nb*8; vb += G2){
                    int b = vb / nb, xb = vb % nb;
                    int t0 = xb*16;
                    for (int idx = tid; idx < 22*64; idx += NTH2){
                        int p = idx >> 6, ci = idx & 63;
                        int gtp = t0 + p;
                        float val = 0.f;
                        if (gtp < LP)
                            val = bn_gelu(ldc(&PA[(b*LP+gtp)*64+ci]), sst[2*ci], sst[2*ci+1], invNp, cs2[ci], cb2[ci]);
                        lds[ci*23 + p] = val;
                    }
                    __syncthreads();
                    float acc[4] = {0.f,0.f,0.f,0.f};
                    for (int ci = 0; ci < 64; ++ci){
                        float r[10];
                        #pragma unroll
                        for (int q = 0; q < 10; ++q) r[q] = lds[ci*23 + tg*4 + q];
                        #pragma unroll
                        for (int kk = 0; kk < 7; ++kk){
                            float w = wv[(kk*64+ci)*64 + co];
                            #pragma unroll
                            for (int j = 0; j < 4; ++j) acc[j] = fmaf(r[j+kk], w, acc[j]);
                        }
                    }
                    #pragma unroll
                    for (int j = 0; j < 4; ++j){
                        int t = t0 + tg*4 + j;
                        if (t < LQ){
                            stc(&PB[(b*LQ+t)*64+co], acc[j]);
                            s += acc[j]; sq += acc[j]*acc[j];
                        }
                    }
                    __syncthreads();
                }
                red[tid] = s; red[NTH2+tid] = sq;
                __syncthreads();
                if (tg == 0 && wg < nb*8){
                    float S  = red[co]+red[co+64]+red[co+128]+red[co+192];
                    float SQ = red[NTH2+co]+red[NTH2+co+64]+red[NTH2+co+128]+red[NTH2+co+192];
                    atomicAdd(&stY[2*co],   S);
                    atomicAdd(&stY[2*co+1], SQ);
                }
            }
            gsync(a.bar);
            // elem (+skip)
            {
                if (tid < 128){ sst[tid] = ldc(&stY[tid]); sst[128+tid] = ldc(&stP[tid]); }
                __syncthreads();
                const float* sa_i = a.sa + 64*i; const float* ba_i = a.ba + 64*i;
                const float* wsk  = a.wskip + 64*i;
                float invNq2 = 1.0f/(8.0f*(float)LQ);
                float s = 0.f, sq = 0.f;
                for (int idx = gt; idx < 8*LQ*64; idx += P2STRIDE){
                    int c  = idx & 63;
                    int bt = idx >> 6;
                    int t  = bt % LQ, b = bt / LQ;
                    float y = bn_gelu(ldc(&PB[idx]), sst[2*c], sst[2*c+1], invNq2, sa_i[c], ba_i[c]);
                    y += bn_gelu(ldc(&PA[(b*LP + t + 6)*64 + c]), sst[128+2*c], sst[128+2*c+1], invNp, cs2[c], cb2[c]) * wsk[c];
                    stc(&PB[idx], y); s += y; sq += y*y;
                }
                red[tid] = s; red[NTH2+tid] = sq;
                __syncthreads();
                if (tg == 0){
                    float S  = red[co]+red[co+64]+red[co+128]+red[co+192];
                    float SQ = red[NTH2+co]+red[NTH2+co+64]+red[NTH2+co+128]+red[NTH2+co+192];
                    atomicAdd(&stY2[2*co],   S);
                    atomicAdd(&stY2[2*co+1], SQ);
                }
            }
            gsync(a.bar);
            stP = stY2; cs2 = a.sb + 64*i; cb2 = a.bbv + 64*i;
            float* tmp = PA; PA = PB; PB = tmp;
            LP = LQ;
        }
        // ---------- OUT stage (WG0): out conv, sample, next window ----------
        if (wg == 0){
            const float invNp = 0.125f;
            if (tid < 64){
                int c = tid;
                float ms = ldc(&stP[2*c]), mq = ldc(&stP[2*c+1]);
                float s2v = cs2[c], b2v = cb2[c];
                float wo = a.wout[c];
                float contrib[8];
                #pragma unroll
                for (int b = 0; b < 8; ++b)
                    contrib[b] = bn_gelu(ldc(&PA[b*64 + c]), ms, mq, invNp, s2v, b2v) * wo;
                #pragma unroll
                for (int b = 0; b < 8; ++b){
                    float v = contrib[b];
                    #pragma unroll
                    for (int off = 32; off > 0; off >>= 1) v += __shfl_down(v, off, 64);
                    if (c == 0) shv[b] = v;
                }
            }
            __syncthreads();
            if (tid == 0){
                float m = 0.f, q = 0.f;
                #pragma unroll
                for (int b = 0; b < 8; ++b){ m += shv[b]; q += shv[b]*shv[b]; }
                m *= 0.125f;
                float var = q*0.125f - m*m;
                float rs = rsqrtf(var + EPSN);
                float so = a.s_out[0], bo = a.b_out[0];
                #pragma unroll
                for (int b = 0; b < 8; ++b){
                    float v = (shv[b]-m)*rs*so + bo;
                    shv[8+b] = v;
                    a.out[b*OUTROW + 3968 + k] = v;
                }
            }
            __syncthreads();
            if (k < NSTEP-1){
                for (int idx = tid; idx < 8*194; idx += NTH2) lds[idx] = ldc(&a.W[idx]);
                __syncthreads();
                float s = 0.f, sq = 0.f;
                for (int idx = tid; idx < 8*194; idx += NTH2){
                    int b = idx / 194, j = idx % 194;
                    float v;
                    if (j < 192)       v = lds[b*194 + j + 2];
                    else if (j == 192) v = a.x[b*XROW + L0IN + 2*(k+1)];
                    else               v = shv[8+b];
                    stc(&a.W[idx], v);
                    s += v; sq += v*v;
                }
                red[tid] = s; red[NTH2+tid] = sq;
                __syncthreads();
                for (int w = 128; w > 0; w >>= 1){
                    if (tid < w){ red[tid] += red[tid+w]; red[NTH2+tid] += red[NTH2+tid+w]; }
                    __syncthreads();
                }
                if (tid == 0){ stc(&a.stx[0], red[0]); stc(&a.stx[1], red[NTH2]); }
            }
        }
        gsync(a.bar);
    }
}

static inline int imin(int a, int b){ return a < b ? a : b; }

extern "C" void kernel_launch(void* const* d_in, const int* in_sizes, int n_in,
                              void* d_out, int out_size, void* d_ws, size_t ws_size,
                              hipStream_t stream){
    const float* x      = (const float*)d_in[0];
    const float* w_in   = (const float*)d_in[1];
    const float* w0     = (const float*)d_in[2];
    const float* w_conv = (const float*)d_in[3];
    const float* w_skip = (const float*)d_in[4];
    const float* w_out  = (const float*)d_in[5];
    const float* s_in   = (const float*)d_in[6];
    const float* b_in   = (const float*)d_in[7];
    const float* s0a    = (const float*)d_in[8];
    const float* b0a    = (const float*)d_in[9];
    const float* s0b    = (const float*)d_in[10];
    const float* b0b    = (const float*)d_in[11];
    const float* sa     = (const float*)d_in[12];
    const float* ba     = (const float*)d_in[13];
    const float* sb     = (const float*)d_in[14];
    const float* bb     = (const float*)d_in[15];
    const float* s_out  = (const float*)d_in[16];
    const float* b_out  = (const float*)d_in[17];
    float* out = (float*)d_out;

    float* ws = (float*)d_ws;
    size_t off = 0;
    float* buf0  = ws + off; off += (size_t)BATCH*L1P1*64;
    float* buf1  = ws + off; off += (size_t)BATCH*L1P1*64;
    float* o_raw = ws + off; off += BATCH*LOUTP1;
    float* W0    = ws + off; off += BATCH*WLEN;
    float* W1    = ws + off; off += BATCH*WLEN;
    float* stats = ws + off; off += 4104;
    float* STX = stats;
    float* STB = stats + 2;
    float* STC = stats + 130;
    float* STOUT = stats + 4098;
    int* bar = (int*)(stats + 4100);

    // phase-2 overlays: tensors on buf0 (dead after phase 1), stat sets on o_raw (dead after finalize1)
    float* P2A_buf = buf0;
    float* P2B_buf = buf0 + 8*91*64;
    float* P2_pst  = o_raw;   // 2*PSTSET = 8192 floats <= 31744

    hipMemsetAsync((void*)bar, 0, 2*sizeof(int), stream);

    // -------- phase 1 (multi-kernel pipeline) --------
    hipMemsetAsync((void*)STX, 0, 2*sizeof(float), stream);
    k_stats_scalar<<<1, 1024, 0, stream>>>(x, XROW, L0IN, STX);

    {
        int Lin = L0IN;
        int Lc = (Lin - 14)/2 + 1;
        // must cover STB..STOUT inclusive (stats+2 .. stats+4099) — round-3 lesson.
        hipMemsetAsync((void*)STB, 0, 4098*sizeof(float), stream);
        k_conv0<<<dim3((Lc+15)/16, BATCH), 256, 0, stream>>>(x, XROW, Lin, Lc, STX,
                                                             w_in, s_in, b_in, w0, buf0, STB);
        {
            int N = BATCH*Lc*64;
            int g = imin((N+255)/256, 2048);
            k_elem<<<g, 256, 0, stream>>>(buf0, Lc, STB, s0a, b0a,
                                          nullptr, 0, nullptr, nullptr, nullptr, nullptr, STC);
        }
        float* A = buf0; float* Bf = buf1;
        const float* stP = STC; const float* cs2 = s0b; const float* cb2 = b0b;
        int LP = Lc;
        for (int i = 0; i < 15; ++i){
            int LQ = LP - 6;
            float* stY  = stats + 258 + i*256;
            float* stY2 = stY + 128;
            k_conv7<<<dim3((LQ+15)/16, BATCH), 256, 0, stream>>>(A, LP, stP, cs2, cb2,
                                                                 w_conv + (size_t)i*7*64*64, Bf, LQ, stY);
            int N = BATCH*LQ*64;
            int g = imin((N+255)/256, 2048);
            k_elem<<<g, 256, 0, stream>>>(Bf, LQ, stY, sa + 64*i, ba + 64*i,
                                          A, LP, stP, cs2, cb2, w_skip + 64*i, stY2);
            stP = stY2; cs2 = sb + 64*i; cb2 = bb + 64*i;
            float* tmp = A; A = Bf; Bf = tmp;
            LP = LQ;
        }
        int g = imin((BATCH*LP+3)/4, 512);
        k_convout<<<g, 256, 0, stream>>>(A, LP, stP, cs2, cb2, w_out, o_raw, STOUT);
    }
    k_finalize1<<<imin((BATCH*LOUTP1+255)/256, 512), 256, 0, stream>>>(o_raw, STOUT, s_out, b_out, out);
    k_initW<<<1, 256, 0, stream>>>(x, out, W0, STX);

    // -------- phase 2: one persistent cooperative kernel --------
    P2A pa;
    pa.x = x; pa.out = out; pa.W = W0; pa.stx = STX;
    pa.bufA = P2A_buf; pa.bufB = P2B_buf; pa.pst = P2_pst; pa.bar = bar;
    pa.w_in = w_in; pa.s_in = s_in; pa.b_in = b_in;
    pa.w0 = w0; pa.wconv = w_conv; pa.wskip = w_skip; pa.wout = w_out;
    pa.s0a = s0a; pa.b0a = b0a; pa.s0b = s0b; pa.b0b = b0b;
    pa.sa = sa; pa.ba = ba; pa.sb = sb; pa.bbv = bb;
    pa.s_out = s_out; pa.b_out = b_out;

    void* kargs[] = { (void*)&pa };
    hipError_t err = hipLaunchCooperativeKernel((const void*)k_phase2, dim3(G2), dim3(NTH2),
                                                kargs, 0, stream);
    if (err != hipSuccess){
        // 64 WGs x 256 threads is trivially co-resident on 256 CUs
        k_phase2<<<dim3(G2), dim3(NTH2), 0, stream>>>(pa);
    }
}